// Round 2
// baseline (793.995 us; speedup 1.0000x reference)
//
#include <hip/hip_runtime.h>

#define NNODES 100000
#define NFEAT  16
#define NEDGES 3200000
#define NLAYERS 4

// ---------------- CSR build ----------------

// histogram of dst into deg[] (deg pre-zeroed)
__global__ __launch_bounds__(256) void hist_kernel(
    const int* __restrict__ dst, int* __restrict__ deg)
{
    int e = blockIdx.x * 256 + threadIdx.x;
    if (e < NEDGES) atomicAdd(&deg[dst[e]], 1);
}

// single-block exclusive scan of deg[NNODES] -> offs[NNODES+1]
#define SCAN_T 1024
#define SCAN_CHUNK 98   // ceil(100000/1024)
__global__ __launch_bounds__(SCAN_T) void scan_kernel(
    const int* __restrict__ deg, int* __restrict__ offs)
{
    __shared__ int part[SCAN_T];
    int t = threadIdx.x;
    int base = t * SCAN_CHUNK;
    int s = 0;
    for (int i = 0; i < SCAN_CHUNK; ++i) {
        int idx = base + i;
        if (idx < NNODES) s += deg[idx];
    }
    part[t] = s;
    __syncthreads();
    // Hillis-Steele inclusive scan
    for (int off = 1; off < SCAN_T; off <<= 1) {
        int v = (t >= off) ? part[t - off] : 0;
        __syncthreads();
        part[t] += v;
        __syncthreads();
    }
    int run = (t == 0) ? 0 : part[t - 1];   // exclusive prefix of this chunk
    for (int i = 0; i < SCAN_CHUNK; ++i) {
        int idx = base + i;
        if (idx < NNODES) { offs[idx] = run; run += deg[idx]; }
    }
    if (t == SCAN_T - 1) offs[NNODES] = run;   // total == NEDGES
}

// scatter edges into CSR slots; cursor pre-initialized to offs[0..NNODES)
__global__ __launch_bounds__(256) void fill_kernel(
    const int*   __restrict__ src,
    const int*   __restrict__ dst,
    const float* __restrict__ wt,
    const float* __restrict__ lw,     // [NLAYERS, NEDGES]
    int*         __restrict__ cursor,
    int*         __restrict__ csr_src,
    float*       __restrict__ csr_w)  // [NLAYERS][NEDGES] separate planes
{
    int e = blockIdx.x * 256 + threadIdx.x;
    if (e >= NEDGES) return;
    int d = dst[e];
    int slot = atomicAdd(&cursor[d], 1);
    float w = wt[e];
    csr_src[slot] = src[e];
    csr_w[0 * NEDGES + slot] = w * lw[0 * NEDGES + e];
    csr_w[1 * NEDGES + slot] = w * lw[1 * NEDGES + e];
    csr_w[2 * NEDGES + slot] = w * lw[2 * NEDGES + e];
    csr_w[3 * NEDGES + slot] = w * lw[3 * NEDGES + e];
}

// ---------------- pull layer ----------------
// 16 lanes per node, one per feature; register accumulate, single write.
// mode 0: out = acc + h0 ; mode 1: out = sigmoid(2*acc)
__global__ __launch_bounds__(256) void pull_layer(
    const int*   __restrict__ offs,
    const int*   __restrict__ csr_src,
    const float* __restrict__ csr_w,   // this layer's plane
    const float* __restrict__ h,
    const float* __restrict__ h0,
    float*       __restrict__ out,
    int mode)
{
    int t = blockIdx.x * 256 + threadIdx.x;
    int n = t >> 4;
    if (n >= NNODES) return;
    int f = t & 15;
    int j0 = offs[n], j1 = offs[n + 1];
    float acc = 0.f;
    int j = j0;
    for (; j + 1 < j1; j += 2) {
        int   s0 = csr_src[j],   s1 = csr_src[j + 1];
        float w0 = csr_w[j],     w1 = csr_w[j + 1];
        float v0 = h[s0 * NFEAT + f];
        float v1 = h[s1 * NFEAT + f];
        acc = fmaf(w0, v0, acc);
        acc = fmaf(w1, v1, acc);
    }
    if (j < j1) acc = fmaf(csr_w[j], h[csr_src[j] * NFEAT + f], acc);

    int o = n * NFEAT + f;
    if (mode == 0) {
        out[o] = acc + h0[o];
    } else {
        out[o] = 1.f / (1.f + expf(-2.f * acc));
    }
}

// ---------------- fallback (round-1 atomic path) ----------------
__global__ __launch_bounds__(256) void scatter_layer(
    const int* __restrict__ src, const int* __restrict__ dst,
    const float* __restrict__ wt, const float* __restrict__ lw,
    const float* __restrict__ h, float* __restrict__ acc)
{
    long t = (long)blockIdx.x * blockDim.x + threadIdx.x;
    int e = (int)(t >> 4);
    if (e >= NEDGES) return;
    int f = (int)(t & 15);
    float w = wt[e] * lw[e];
    atomicAdd(&acc[dst[e] * NFEAT + f], w * h[src[e] * NFEAT + f]);
}
__global__ __launch_bounds__(256) void sigmoid_inplace(float* __restrict__ out, int n)
{
    int i = blockIdx.x * blockDim.x + threadIdx.x;
    if (i < n) out[i] = 1.f / (1.f + expf(-2.f * out[i]));
}

// ---------------- launch ----------------
extern "C" void kernel_launch(void* const* d_in, const int* in_sizes, int n_in,
                              void* d_out, int out_size, void* d_ws, size_t ws_size,
                              hipStream_t stream)
{
    const float* h0 = (const float*)d_in[0];
    const int*   ei = (const int*)d_in[1];     // int32 (JAX x64 off)
    const float* wt = (const float*)d_in[2];
    const float* lw = (const float*)d_in[3];

    const int* src = ei;
    const int* dst = ei + NEDGES;

    const size_t hbytes = (size_t)NNODES * NFEAT * sizeof(float);

    // workspace layout
    size_t off_offs   = 0;                         // int[NNODES+1]
    size_t off_cursor = 400128;                    // int[NNODES] (doubles as deg)
    size_t off_csrsrc = 800256;                    // int[NEDGES]
    size_t off_csrw   = off_csrsrc + (size_t)NEDGES * 4;            // float[4][NEDGES]
    size_t off_hbuf   = off_csrw + (size_t)4 * NEDGES * 4;          // float[NNODES*16]
    size_t need       = off_hbuf + hbytes;

    if (ws_size < need) {
        // fallback: atomic push path (round-1)
        float* hw = (float*)d_ws;
        float* ho = (float*)d_out;
        dim3 blk(256), grd(((long)NEDGES * 16 + 255) / 256);
        hipMemcpyAsync(hw, h0, hbytes, hipMemcpyDeviceToDevice, stream);
        scatter_layer<<<grd, blk, 0, stream>>>(src, dst, wt, lw + 0L * NEDGES, h0, hw);
        hipMemcpyAsync(ho, h0, hbytes, hipMemcpyDeviceToDevice, stream);
        scatter_layer<<<grd, blk, 0, stream>>>(src, dst, wt, lw + 1L * NEDGES, hw, ho);
        hipMemcpyAsync(hw, h0, hbytes, hipMemcpyDeviceToDevice, stream);
        scatter_layer<<<grd, blk, 0, stream>>>(src, dst, wt, lw + 2L * NEDGES, ho, hw);
        hipMemsetAsync(ho, 0, hbytes, stream);
        scatter_layer<<<grd, blk, 0, stream>>>(src, dst, wt, lw + 3L * NEDGES, hw, ho);
        int n = NNODES * NFEAT;
        sigmoid_inplace<<<(n + 255) / 256, 256, 0, stream>>>(ho, n);
        return;
    }

    char* ws = (char*)d_ws;
    int*   offs    = (int*)  (ws + off_offs);
    int*   cursor  = (int*)  (ws + off_cursor);
    int*   csr_src = (int*)  (ws + off_csrsrc);
    float* csr_w   = (float*)(ws + off_csrw);
    float* hbuf    = (float*)(ws + off_hbuf);
    float* hout    = (float*)d_out;

    // ---- build CSR ----
    hipMemsetAsync(cursor, 0, (size_t)NNODES * 4, stream);             // deg = 0
    hist_kernel<<<(NEDGES + 255) / 256, 256, 0, stream>>>(dst, cursor);
    scan_kernel<<<1, SCAN_T, 0, stream>>>(cursor, offs);
    hipMemcpyAsync(cursor, offs, (size_t)NNODES * 4, hipMemcpyDeviceToDevice, stream);
    fill_kernel<<<(NEDGES + 255) / 256, 256, 0, stream>>>(src, dst, wt, lw,
                                                          cursor, csr_src, csr_w);

    // ---- 4 pull layers ----
    dim3 blk(256), grd((NNODES * 16) / 256);   // 6250 blocks, exact
    // L0: h0 -> hbuf (+h0)
    pull_layer<<<grd, blk, 0, stream>>>(offs, csr_src, csr_w + 0L * NEDGES, h0,   h0, hbuf, 0);
    // L1: hbuf -> hout (+h0)
    pull_layer<<<grd, blk, 0, stream>>>(offs, csr_src, csr_w + 1L * NEDGES, hbuf, h0, hout, 0);
    // L2: hout -> hbuf (+h0)
    pull_layer<<<grd, blk, 0, stream>>>(offs, csr_src, csr_w + 2L * NEDGES, hout, h0, hbuf, 0);
    // L3: hbuf -> hout, sigmoid(2*acc)
    pull_layer<<<grd, blk, 0, stream>>>(offs, csr_src, csr_w + 3L * NEDGES, hbuf, h0, hout, 1);
}

// Round 3
// 740.506 us; speedup vs baseline: 1.0722x; 1.0722x over previous
//
#include <hip/hip_runtime.h>
#include <hip/hip_fp16.h>

#define NNODES 100000
#define NFEAT  16
#define NEDGES 3200000
#define NLAYERS 4

// ---------------- CSR build ----------------

// histogram of dst into deg[] (deg pre-zeroed)
__global__ __launch_bounds__(256) void hist_kernel(
    const int* __restrict__ dst, int* __restrict__ deg)
{
    int e = blockIdx.x * 256 + threadIdx.x;
    if (e < NEDGES) atomicAdd(&deg[dst[e]], 1);
}

// single-block exclusive scan of deg[NNODES] -> offs[NNODES+1]
#define SCAN_T 1024
#define SCAN_CHUNK 98   // ceil(100000/1024)
__global__ __launch_bounds__(SCAN_T) void scan_kernel(
    const int* __restrict__ deg, int* __restrict__ offs)
{
    __shared__ int part[SCAN_T];
    int t = threadIdx.x;
    int base = t * SCAN_CHUNK;
    int s = 0;
    for (int i = 0; i < SCAN_CHUNK; ++i) {
        int idx = base + i;
        if (idx < NNODES) s += deg[idx];
    }
    part[t] = s;
    __syncthreads();
    for (int off = 1; off < SCAN_T; off <<= 1) {
        int v = (t >= off) ? part[t - off] : 0;
        __syncthreads();
        part[t] += v;
        __syncthreads();
    }
    int run = (t == 0) ? 0 : part[t - 1];
    for (int i = 0; i < SCAN_CHUNK; ++i) {
        int idx = base + i;
        if (idx < NNODES) { offs[idx] = run; run += deg[idx]; }
    }
    if (t == SCAN_T - 1) offs[NNODES] = run;
}

// packed CSR entry: 3 dwords per edge  {src, half2(w0,w1), half2(w2,w3)}
__global__ __launch_bounds__(256) void fill_kernel(
    const int*   __restrict__ src,
    const int*   __restrict__ dst,
    const float* __restrict__ wt,
    const float* __restrict__ lw,     // [NLAYERS, NEDGES]
    int*         __restrict__ cursor,
    unsigned int* __restrict__ csr)   // [NEDGES*3]
{
    int e = blockIdx.x * 256 + threadIdx.x;
    if (e >= NEDGES) return;
    int d = dst[e];
    int slot = atomicAdd(&cursor[d], 1);
    float w = wt[e];
    __half2 p01, p23;
    p01.x = __float2half_rn(w * lw[0 * NEDGES + e]);
    p01.y = __float2half_rn(w * lw[1 * NEDGES + e]);
    p23.x = __float2half_rn(w * lw[2 * NEDGES + e]);
    p23.y = __float2half_rn(w * lw[3 * NEDGES + e]);
    unsigned int* p = csr + 3u * (unsigned int)slot;
    p[0] = (unsigned int)src[e];
    p[1] = *(const unsigned int*)&p01;
    p[2] = *(const unsigned int*)&p23;
}

// ---------------- pull layer ----------------
// 16 lanes per node; register accumulate; one write per output element.
// K: layer index (selects packed weight). IN16: gather source is f16.
// SIG: final layer (sigmoid, f32 out) else (acc + h0, f16 out).
template<int K, bool IN16, bool SIG>
__global__ __launch_bounds__(256) void pull_kernel(
    const int*          __restrict__ offs,
    const unsigned int* __restrict__ csr,
    const void*         __restrict__ hin,
    const float*        __restrict__ h0,
    void*               __restrict__ hout)
{
    int t = blockIdx.x * 256 + threadIdx.x;
    int n = t >> 4;
    if (n >= NNODES) return;
    int f = t & 15;
    int j0 = offs[n], j1 = offs[n + 1];

    const __half* h16 = (const __half*)hin;
    const float*  h32 = (const float*)hin;

    float acc = 0.f;
    int j = j0;
    for (; j + 1 < j1; j += 2) {
        const unsigned int* p0 = csr + 3u * (unsigned int)j;
        const unsigned int* p1 = p0 + 3;
        unsigned int s0 = p0[0];
        unsigned int s1 = p1[0];
        unsigned int wb0 = p0[1 + (K >> 1)];
        unsigned int wb1 = p1[1 + (K >> 1)];
        float hv0 = IN16 ? __half2float(h16[(size_t)s0 * NFEAT + f])
                         : h32[(size_t)s0 * NFEAT + f];
        float hv1 = IN16 ? __half2float(h16[(size_t)s1 * NFEAT + f])
                         : h32[(size_t)s1 * NFEAT + f];
        __half2 wp0 = *(const __half2*)&wb0;
        __half2 wp1 = *(const __half2*)&wb1;
        float w0 = (K & 1) ? __high2float(wp0) : __low2float(wp0);
        float w1 = (K & 1) ? __high2float(wp1) : __low2float(wp1);
        acc = fmaf(w0, hv0, acc);
        acc = fmaf(w1, hv1, acc);
    }
    if (j < j1) {
        const unsigned int* p0 = csr + 3u * (unsigned int)j;
        unsigned int s0 = p0[0];
        unsigned int wb0 = p0[1 + (K >> 1)];
        __half2 wp0 = *(const __half2*)&wb0;
        float w0 = (K & 1) ? __high2float(wp0) : __low2float(wp0);
        float hv0 = IN16 ? __half2float(h16[(size_t)s0 * NFEAT + f])
                         : h32[(size_t)s0 * NFEAT + f];
        acc = fmaf(w0, hv0, acc);
    }

    int o = n * NFEAT + f;
    if (SIG) {
        ((float*)hout)[o] = 1.f / (1.f + expf(-2.f * acc));
    } else {
        ((__half*)hout)[o] = __float2half_rn(acc + h0[o]);
    }
}

// ---------------- fallback (round-1 atomic push path) ----------------
__global__ __launch_bounds__(256) void scatter_layer(
    const int* __restrict__ src, const int* __restrict__ dst,
    const float* __restrict__ wt, const float* __restrict__ lw,
    const float* __restrict__ h, float* __restrict__ acc)
{
    long t = (long)blockIdx.x * blockDim.x + threadIdx.x;
    int e = (int)(t >> 4);
    if (e >= NEDGES) return;
    int f = (int)(t & 15);
    float w = wt[e] * lw[e];
    atomicAdd(&acc[dst[e] * NFEAT + f], w * h[src[e] * NFEAT + f]);
}
__global__ __launch_bounds__(256) void sigmoid_inplace(float* __restrict__ out, int n)
{
    int i = blockIdx.x * blockDim.x + threadIdx.x;
    if (i < n) out[i] = 1.f / (1.f + expf(-2.f * out[i]));
}

// ---------------- launch ----------------
extern "C" void kernel_launch(void* const* d_in, const int* in_sizes, int n_in,
                              void* d_out, int out_size, void* d_ws, size_t ws_size,
                              hipStream_t stream)
{
    const float* h0 = (const float*)d_in[0];
    const int*   ei = (const int*)d_in[1];     // int32 (JAX x64 off)
    const float* wt = (const float*)d_in[2];
    const float* lw = (const float*)d_in[3];

    const int* src = ei;
    const int* dst = ei + NEDGES;

    const size_t hbytes = (size_t)NNODES * NFEAT * sizeof(float);

    // workspace layout
    size_t off_offs   = 0;                                   // int[NNODES+1]
    size_t off_cursor = 400128;                              // int[NNODES]
    size_t off_csr    = 800256;                              // u32[3*NEDGES] = 38.4 MB
    size_t off_hbA    = off_csr + (size_t)3 * NEDGES * 4;    // f16[NNODES*16] = 3.2 MB
    size_t off_hbB    = off_hbA + (size_t)NNODES * NFEAT * 2;
    size_t need       = off_hbB + (size_t)NNODES * NFEAT * 2;

    if (ws_size < need) {
        // fallback: atomic push path
        float* hw = (float*)d_ws;
        float* ho = (float*)d_out;
        dim3 blk(256), grd(((long)NEDGES * 16 + 255) / 256);
        hipMemcpyAsync(hw, h0, hbytes, hipMemcpyDeviceToDevice, stream);
        scatter_layer<<<grd, blk, 0, stream>>>(src, dst, wt, lw + 0L * NEDGES, h0, hw);
        hipMemcpyAsync(ho, h0, hbytes, hipMemcpyDeviceToDevice, stream);
        scatter_layer<<<grd, blk, 0, stream>>>(src, dst, wt, lw + 1L * NEDGES, hw, ho);
        hipMemcpyAsync(hw, h0, hbytes, hipMemcpyDeviceToDevice, stream);
        scatter_layer<<<grd, blk, 0, stream>>>(src, dst, wt, lw + 2L * NEDGES, ho, hw);
        hipMemsetAsync(ho, 0, hbytes, stream);
        scatter_layer<<<grd, blk, 0, stream>>>(src, dst, wt, lw + 3L * NEDGES, hw, ho);
        int n = NNODES * NFEAT;
        sigmoid_inplace<<<(n + 255) / 256, 256, 0, stream>>>(ho, n);
        return;
    }

    char* ws = (char*)d_ws;
    int*          offs   = (int*)(ws + off_offs);
    int*          cursor = (int*)(ws + off_cursor);
    unsigned int* csr    = (unsigned int*)(ws + off_csr);
    __half*       hbA    = (__half*)(ws + off_hbA);
    __half*       hbB    = (__half*)(ws + off_hbB);
    float*        hout   = (float*)d_out;

    // ---- build packed CSR ----
    hipMemsetAsync(cursor, 0, (size_t)NNODES * 4, stream);
    hist_kernel<<<(NEDGES + 255) / 256, 256, 0, stream>>>(dst, cursor);
    scan_kernel<<<1, SCAN_T, 0, stream>>>(cursor, offs);
    hipMemcpyAsync(cursor, offs, (size_t)NNODES * 4, hipMemcpyDeviceToDevice, stream);
    fill_kernel<<<(NEDGES + 255) / 256, 256, 0, stream>>>(src, dst, wt, lw, cursor, csr);

    // ---- 4 pull layers ----
    dim3 blk(256), grd((NNODES * 16 + 255) / 256);
    pull_kernel<0, false, false><<<grd, blk, 0, stream>>>(offs, csr, h0,  h0, hbA);
    pull_kernel<1, true,  false><<<grd, blk, 0, stream>>>(offs, csr, hbA, h0, hbB);
    pull_kernel<2, true,  false><<<grd, blk, 0, stream>>>(offs, csr, hbB, h0, hbA);
    pull_kernel<3, true,  true ><<<grd, blk, 0, stream>>>(offs, csr, hbA, h0, hout);
}